// Round 13
// baseline (307.110 us; speedup 1.0000x reference)
//
#include <hip/hip_runtime.h>
#include <stdint.h>

#define FD 128   // feature dim
#define NG 8     // graphs
#define NC 10    // classes
#define MAXB 1024           // max buckets
#define CHUNK 8192          // edges per sort block (8/thread @ 1024 thr)
#define BFPAD 4             // bucket_fill stride (ints): 4 buckets/64B line

typedef __attribute__((ext_vector_type(8))) short bf16x8;
typedef __attribute__((ext_vector_type(4))) float f32x4;
typedef __attribute__((ext_vector_type(2))) float f32x2;

__device__ __forceinline__ float bf2f(uint16_t u){
    union { uint32_t i; float f; } v; v.i = ((uint32_t)u) << 16; return v.f;
}
__device__ __forceinline__ uint16_t f2bf(float f){
    union { float f; uint32_t i; } v; v.f = f;
    uint32_t r = v.i + 0x7fff + ((v.i >> 16) & 1);
    return (uint16_t)(r >> 16);
}

// ---- fp8 e4m3 conversions (HW path with manual fallback) ----
#if __has_builtin(__builtin_amdgcn_cvt_pk_f32_fp8) && __has_builtin(__builtin_amdgcn_cvt_pk_fp8_f32)
__device__ __forceinline__ f32x2 fp8lo2f(uint32_t p){
    return __builtin_amdgcn_cvt_pk_f32_fp8((int)p, false);
}
__device__ __forceinline__ f32x2 fp8hi2f(uint32_t p){
    return __builtin_amdgcn_cvt_pk_f32_fp8((int)p, true);
}
__device__ __forceinline__ uint32_t pk4fp8(float a, float b, float c, float d){
    int u = 0;
    u = __builtin_amdgcn_cvt_pk_fp8_f32(a, b, u, false);
    u = __builtin_amdgcn_cvt_pk_fp8_f32(c, d, u, true);
    return (uint32_t)u;
}
#else
__device__ __forceinline__ float fp8tof(uint32_t b){
    union { uint32_t i; float f; } v;
    v.i = ((b & 0x7f) << 20) | ((b & 0x80) << 24);
    return v.f * 0x1p120f;
}
__device__ __forceinline__ f32x2 fp8lo2f(uint32_t p){
    return (f32x2){fp8tof(p & 0xff), fp8tof((p >> 8) & 0xff)};
}
__device__ __forceinline__ f32x2 fp8hi2f(uint32_t p){
    return (f32x2){fp8tof((p >> 16) & 0xff), fp8tof((p >> 24) & 0xff)};
}
__device__ __forceinline__ uint32_t f2fp8(float f){
    union { float f; uint32_t i; } v; v.f = f;
    uint32_t s = (v.i >> 24) & 0x80;
    float a = fabsf(f);
    if (a < 0x1p-10f) return s;
    if (a > 448.f) return s | 0x7e;
    v.f = a;
    uint32_t r = v.i + 0x7ffff + ((v.i >> 20) & 1);
    int e = (int)(r >> 23) - 127 + 7;
    uint32_t m = (r >> 20) & 7;
    if (e <= 0){
        uint32_t q = (uint32_t)(a * 512.f + 0.5f);
        return s | (q > 7 ? 8 : q);
    }
    if (e > 15) return s | 0x7e;
    return s | ((uint32_t)e << 3) | m;
}
__device__ __forceinline__ uint32_t pk4fp8(float a, float b, float c, float d){
    return (uint32_t)f2fp8(a) | ((uint32_t)f2fp8(b)<<8) |
           ((uint32_t)f2fp8(c)<<16) | ((uint32_t)f2fp8(d)<<24);
}
#endif

// ============ prep: weight conversion + zero-init ============
__global__ __launch_bounds__(256) void k_prep(const float* __restrict__ W1,
        const float* __restrict__ W2, uint16_t* Wf1, uint16_t* Wf2,
        int B, int* __restrict__ bfD, int* __restrict__ bfS,
        float* __restrict__ pool, int* __restrict__ ctr){
    int t = threadIdx.x;
    int id = blockIdx.x*256 + t;           // grid = 128 blocks -> 32768 threads
    {   // weight fragment conversion (exactly 2*16384 entries)
        int w = id >> 14;
        int r = id & 16383;
        int j = r & 7, frag = r >> 3;
        int lane = frag & 63, t2 = frag >> 6;
        int n = t2 & 7, kk = t2 >> 3;
        int k = kk*32 + (lane>>4)*8 + j;
        int col = n*16 + (lane&15);
        float v = (w ? W2 : W1)[k*128 + col];
        (w ? Wf2 : Wf1)[r] = f2bf(v);
    }
    for (int i = id; i < B*BFPAD; i += 32768){ bfD[i] = 0; bfS[i] = 0; }
    if (id < NG*FD) pool[id] = 0.f;
    if (id == 0) *ctr = 0;
}

// ============ FUSED: merged D+S sort | GEMM1 (2 block ranges) ============
// R8/R12-validated: edge-pass cost ~ per-block fixed work + packed 16B
// stores. R13: CHUNK 8192 halves sort-block instances (98) so LDS init,
// scans and reserve passes amortize over 2x edges.
__global__ __launch_bounds__(1024) void k_gemm_scatter(const int* __restrict__ ei,
        int E, int B, int shift, int CAP, int C,
        int* __restrict__ bfD, int* __restrict__ bfS,
        uint32_t* __restrict__ tempD, uint16_t* __restrict__ tempS,
        const float* __restrict__ X, const uint16_t* __restrict__ Wf,
        uint8_t* __restrict__ out8, int N){
    __shared__ __align__(16) char lds[61440];
    int t = threadIdx.x;
    int lmask = (1<<shift) - 1;
    if ((int)blockIdx.x < C){
        uint32_t* payD = (uint32_t*)lds;          // 11264 u32 = 45056B
        uint16_t* payS = (uint16_t*)lds;          // 15360 u16 = 30720B (reuse)
        int* cnt  = (int*)(lds + 45056);
        int* off  = cnt  + MAXB;
        int* resv = off  + MAXB;
        int* scr  = resv + MAXB;                  // + 16384B = 61440
        // ---- read chunk ONCE ----
        int c = blockIdx.x;
        int e0 = c*CHUNK, e1 = min(E, e0+CHUNK);
        int ss[8], dd[8];
        #pragma unroll
        for (int k=0;k<8;k++){
            int e = e0 + t + k*1024;
            bool ok = e < e1;
            ss[k] = ok ? ei[e]   : -1;
            dd[k] = ok ? ei[E+e] : -1;
        }
        // ---------- D phase: (loc<<20|src) u32, pad-4 ----------
        for (int i=t;i<11264;i+=1024) payD[i] = 0xFFFFFFFFu;
        for (int i=t;i<B;i+=1024) cnt[i] = 0;
        __syncthreads();
        int bb[8], pl[8];
        #pragma unroll
        for (int k=0;k<8;k++){
            bb[k] = -1;
            if (dd[k] >= 0){
                int b = dd[k] >> shift;
                bb[k] = b;
                pl[k] = atomicAdd(&cnt[b], 1);
            }
        }
        __syncthreads();
        int v = (t < B) ? ((cnt[t]+3) & ~3) : 0;
        scr[t] = v; __syncthreads();
        for (int o=1;o<1024;o<<=1){ int u=(t>=o)?scr[t-o]:0; __syncthreads(); scr[t]+=u; __syncthreads(); }
        if (t < B) off[t] = scr[t] - v;
        __syncthreads();
        int totalPad = scr[1023];
        #pragma unroll
        for (int k=0;k<8;k++)
            if (bb[k] >= 0)
                payD[off[bb[k]] + pl[k]] = ((uint32_t)(dd[k] & lmask) << 20) | (uint32_t)ss[k];
        for (int b=t;b<B;b+=1024){
            int pc = (cnt[b]+3) & ~3;
            resv[b] = pc ? atomicAdd(&bfD[b*BFPAD], pc) : 0;
        }
        __syncthreads();
        for (int g=t; g < (totalPad>>2); g += 1024){
            int pos = g << 2;
            int lo = 0, hi = B-1;   // largest b with off[b] <= pos
            while (lo < hi){ int mid=(lo+hi+1)>>1; if (off[mid] <= pos) lo = mid; else hi = mid-1; }
            int rel = resv[lo] + (pos - off[lo]);
            if (rel + 4 <= CAP){
                uint4 w4 = *(const uint4*)&payD[pos];
                *(uint4*)&tempD[(size_t)lo*CAP + rel] = w4;
            }
        }
        __syncthreads();   // all payD/off/resv reads done before LDS reuse
        // ---------- S phase: (src&lmask) u16, pad-8 ----------
        for (int i=t;i<15360;i+=1024) payS[i] = 0xFFFF;
        for (int i=t;i<B;i+=1024) cnt[i] = 0;
        __syncthreads();
        #pragma unroll
        for (int k=0;k<8;k++){
            bb[k] = -1;
            if (ss[k] >= 0){
                int b = ss[k] >> shift;
                bb[k] = b;
                pl[k] = atomicAdd(&cnt[b], 1);
            }
        }
        __syncthreads();
        v = (t < B) ? ((cnt[t]+7) & ~7) : 0;
        scr[t] = v; __syncthreads();
        for (int o=1;o<1024;o<<=1){ int u=(t>=o)?scr[t-o]:0; __syncthreads(); scr[t]+=u; __syncthreads(); }
        if (t < B) off[t] = scr[t] - v;
        __syncthreads();
        totalPad = scr[1023];
        #pragma unroll
        for (int k=0;k<8;k++)
            if (bb[k] >= 0) payS[off[bb[k]] + pl[k]] = (uint16_t)(ss[k] & lmask);
        for (int b=t;b<B;b+=1024){
            int pc = (cnt[b]+7) & ~7;
            resv[b] = pc ? atomicAdd(&bfS[b*BFPAD], pc) : 0;
        }
        __syncthreads();
        for (int g=t; g < (totalPad>>3); g += 1024){
            int pos = g << 3;
            int lo = 0, hi = B-1;
            while (lo < hi){ int mid=(lo+hi+1)>>1; if (off[mid] <= pos) lo = mid; else hi = mid-1; }
            int rel = resv[lo] + (pos - off[lo]);
            if (rel + 8 <= CAP){
                uint4 w4 = *(const uint4*)&payS[pos];
                *(uint4*)&tempS[(size_t)lo*CAP + rel] = w4;
            }
        }
        return;
    }
    // ---------------- GEMM1 path: 256 rows/block, 16 waves ----------------
    int wave = t>>6, lane = t&63, quad = lane>>4, low = lane&15;
    int rowA  = (blockIdx.x - C)*256 + wave*16 + low;
    int rowAc = min(rowA, N-1);
    const float* arow = X + (size_t)rowAc*FD;
    bf16x8 ah[4];
    #pragma unroll
    for (int kk=0;kk<4;kk++){
        f32x4 f0 = *(const f32x4*)(arow + kk*32 + quad*8);
        f32x4 f1 = *(const f32x4*)(arow + kk*32 + quad*8 + 4);
        #pragma unroll
        for (int j=0;j<4;j++) ah[kk][j]   = (short)f2bf(f0[j]);
        #pragma unroll
        for (int j=0;j<4;j++) ah[kk][j+4] = (short)f2bf(f1[j]);
    }
    f32x4 acc[8];
    #pragma unroll
    for (int n=0;n<8;n++) acc[n] = (f32x4){0.f,0.f,0.f,0.f};
    #pragma unroll
    for (int kk=0;kk<4;kk++){
        #pragma unroll
        for (int n=0;n<8;n++){
            bf16x8 bh = *(const bf16x8*)(Wf + ((size_t)((kk*8+n)*64 + lane))*8);
            acc[n] = __builtin_amdgcn_mfma_f32_16x16x32_bf16(bh, ah[kk], acc[n], 0, 0, 0);
        }
    }
    if (rowA < N){
        uint8_t* orow = out8 + (size_t)rowA*FD;
        #pragma unroll
        for (int n=0;n<8;n++){
            uint32_t pk = pk4fp8(acc[n][0], acc[n][1], acc[n][2], acc[n][3]);
            *(uint32_t*)(orow + n*16 + quad*4) = pk;
        }
    }
}

// ============ per-bucket build: row_off/deg_in/csr from tempD; isqo from tempS ============
__global__ __launch_bounds__(256) void k_build(const uint32_t* __restrict__ tempD,
        const uint16_t* __restrict__ tempS,
        const int* __restrict__ bfD, const int* __restrict__ bfS,
        int B, int shift, int N, int CAP,
        int* __restrict__ row_off, int* __restrict__ deg_in,
        float* __restrict__ isqo, int* __restrict__ csr){
    __shared__ int cnt_[MAXB];
    __shared__ int off_[MAXB];
    int b = blockIdx.x, t = threadIdx.x;
    int range = 1<<shift, nb0 = b<<shift;
    int fill = min(bfD[b*BFPAD], CAP);
    const uint32_t* seg = tempD + (size_t)b*CAP;
    for (int i=t;i<range;i+=256) cnt_[i]=0;
    __syncthreads();
    for (int i=t;i<fill;i+=256){
        int loc = (int)(seg[i] >> 20);
        if (loc < range) atomicAdd(&cnt_[loc], 1);   // skip pad sentinels
    }
    __syncthreads();
    if (range == 64){
        if (t < 64){
            int v = cnt_[t];
            int inc = v;
            #pragma unroll
            for (int o=1;o<64;o<<=1){
                int u = __shfl_up(inc, o);
                if (t >= o) inc += u;
            }
            off_[t] = inc - v;
        }
    } else if (t == 0){
        int run = 0;
        for (int i=0;i<range;i++){ off_[i]=run; run+=cnt_[i]; }
    }
    __syncthreads();
    int base = b*CAP;
    for (int i=t;i<range;i+=256){
        int node = nb0 + i;
        if (node < N){
            row_off[node] = base + off_[i];
            deg_in[node]  = cnt_[i];
        }
    }
    __syncthreads();
    int* csrb = csr + (size_t)base;
    for (int i=t;i<fill;i+=256){
        uint32_t v = seg[i];
        int loc = (int)(v >> 20);
        if (loc < range){
            int p = atomicAdd(&off_[loc], 1);
            csrb[p] = (int)(v & 0xFFFFFu);
        }
    }
    __syncthreads();
    // ---- phase B: out-degree histogram from sorted src stream ----
    for (int i=t;i<range;i+=256) cnt_[i]=0;
    __syncthreads();
    int fillS = min(bfS[b*BFPAD], CAP);
    const uint16_t* segS = tempS + (size_t)b*CAP;
    for (int i=t;i<fillS;i+=256){
        int v = (int)segS[i];
        if (v < range) atomicAdd(&cnt_[v], 1);
    }
    __syncthreads();
    for (int i=t;i<range;i+=256){
        int node = nb0 + i;
        if (node < N) isqo[node] = rsqrtf((float)max(cnt_[i], 1));
    }
}

// ============ SpMM row-gather core: quarter-wave, 8B/lane, depth-8 ============
template<bool WSCALE>
__device__ __forceinline__ void spmm_row(const uint2* __restrict__ tp,
        const int* __restrict__ csr_src, const float* __restrict__ isqo,
        int e0, int e1, int l, int qb,
        f32x2& a01, f32x2& a23, f32x2& a45, f32x2& a67){
    for (int base = e0; base < e1; base += 16){
        int my = 0;
        if (base + l < e1) my = csr_src[base + l];
        int cnt = min(16, e1 - base);
        for (int j0 = 0; j0 < cnt; j0 += 8){
            int ss[8];
            #pragma unroll
            for (int k=0;k<8;k++)
                ss[k] = __shfl(my, qb + min(j0 + k, cnt-1));
            uint2 p[8]; float w[8];
            #pragma unroll
            for (int k=0;k<8;k++)
                p[k] = tp[(size_t)ss[k]*16 + l];
            if (WSCALE){
                #pragma unroll
                for (int k=0;k<8;k++) w[k] = isqo[ss[k]];
            }
            #pragma unroll
            for (int k=0;k<8;k++){
                if (j0 + k < cnt){
                    if (WSCALE){
                        a01 += fp8lo2f(p[k].x)*w[k]; a23 += fp8hi2f(p[k].x)*w[k];
                        a45 += fp8lo2f(p[k].y)*w[k]; a67 += fp8hi2f(p[k].y)*w[k];
                    } else {
                        a01 += fp8lo2f(p[k].x); a23 += fp8hi2f(p[k].x);
                        a45 += fp8lo2f(p[k].y); a67 += fp8hi2f(p[k].y);
                    }
                }
            }
        }
    }
}

// ============ Fused: SpMM layer-1 -> LDS h -> GEMM W2 -> fp8 (scaled) ============
__global__ __launch_bounds__(256, 6) void k_spmm_gemm(const uint8_t* __restrict__ tmp8,
        const int* __restrict__ row_off, const int* __restrict__ deg_in,
        const int* __restrict__ csr_src, const float* __restrict__ isqo,
        const float* __restrict__ bias, const uint16_t* __restrict__ Wf,
        uint8_t* __restrict__ out8, int N){
    __shared__ __align__(16) uint16_t hsrow[32][136];   // +8 shorts pad
    int tid = threadIdx.x;
    int l = tid & 15, qid = tid >> 4, qb = (tid & 63) & 48;
    const uint2* tp = (const uint2*)tmp8;
    f32x4 bv0 = *(const f32x4*)(bias + l*8);
    f32x4 bv1 = *(const f32x4*)(bias + l*8 + 4);
    #pragma unroll
    for (int i = 0; i < 2; i++){
        int rowL = qid*2 + i;
        int node = blockIdx.x*32 + rowL;
        int e0 = 0, e1 = 0;
        if (node < N){ e0 = row_off[node]; e1 = e0 + deg_in[node]; }
        f32x2 a01={0.f,0.f}, a23={0.f,0.f}, a45={0.f,0.f}, a67={0.f,0.f};
        spmm_row<true>(tp, csr_src, isqo, e0, e1, l, qb, a01, a23, a45, a67);
        float isq = rsqrtf((float)max(e1 - e0, 1));
        float r0 = fmaxf(a01.x*isq + bv0[0], 0.f);
        float r1 = fmaxf(a01.y*isq + bv0[1], 0.f);
        float r2 = fmaxf(a23.x*isq + bv0[2], 0.f);
        float r3 = fmaxf(a23.y*isq + bv0[3], 0.f);
        float r4 = fmaxf(a45.x*isq + bv1[0], 0.f);
        float r5 = fmaxf(a45.y*isq + bv1[1], 0.f);
        float r6 = fmaxf(a67.x*isq + bv1[2], 0.f);
        float r7 = fmaxf(a67.y*isq + bv1[3], 0.f);
        uint4 o;
        o.x = (uint32_t)f2bf(r0) | ((uint32_t)f2bf(r1) << 16);
        o.y = (uint32_t)f2bf(r2) | ((uint32_t)f2bf(r3) << 16);
        o.z = (uint32_t)f2bf(r4) | ((uint32_t)f2bf(r5) << 16);
        o.w = (uint32_t)f2bf(r6) | ((uint32_t)f2bf(r7) << 16);
        if (node >= N) o = (uint4){0u,0u,0u,0u};
        *(uint4*)(&hsrow[rowL][l*8]) = o;
    }
    __syncthreads();
    int wave = tid>>6, lane = tid&63, quad = lane>>4, low = lane&15;
    int rowL = (wave&1)*16 + low;
    int rowA = blockIdx.x*32 + rowL;
    int nb0 = (wave>>1)*4;
    bf16x8 ah[4];
    #pragma unroll
    for (int kk=0;kk<4;kk++)
        ah[kk] = *(const bf16x8*)(&hsrow[rowL][kk*32 + quad*8]);
    f32x4 acc[4];
    #pragma unroll
    for (int n=0;n<4;n++) acc[n] = (f32x4){0.f,0.f,0.f,0.f};
    #pragma unroll
    for (int kk=0;kk<4;kk++){
        #pragma unroll
        for (int n2=0;n2<4;n2++){
            int n = nb0 + n2;
            bf16x8 bh = *(const bf16x8*)(Wf + ((size_t)((kk*8+n)*64 + lane))*8);
            acc[n2] = __builtin_amdgcn_mfma_f32_16x16x32_bf16(bh, ah[kk], acc[n2], 0, 0, 0);
        }
    }
    if (rowA < N){
        float sc = isqo[rowA];   // fold out-deg scale: spmm_pool needs no isqo loads
        uint8_t* orow = out8 + (size_t)rowA*FD;
        #pragma unroll
        for (int n2=0;n2<4;n2++){
            int n = nb0 + n2;
            uint32_t pk = pk4fp8(acc[n2][0]*sc, acc[n2][1]*sc, acc[n2][2]*sc, acc[n2][3]*sc);
            *(uint32_t*)(orow + n*16 + quad*4) = pk;
        }
    }
}

// ============ Fused: SpMM layer-2 -> pool -> (last block) final softmax ============
__global__ __launch_bounds__(256, 6) void k_spmm_pool(const uint8_t* __restrict__ tmp8,
        const int* __restrict__ row_off, const int* __restrict__ deg_in,
        const int* __restrict__ csr_src,
        const float* __restrict__ bias, const int* __restrict__ n2g,
        float* __restrict__ pool, int N,
        const float* __restrict__ Wl, const float* __restrict__ bl,
        float* __restrict__ out, int* __restrict__ ctr){
    __shared__ float sacc[NG*FD];
    __shared__ int isLast;
    __shared__ int ub[NG+1];
    __shared__ float logits[NG][NC];
    int tid = threadIdx.x;
    for (int i = tid; i < NG*FD; i += 256) sacc[i] = 0.f;
    __syncthreads();
    int l = tid & 15, qid = tid >> 4, qb = (tid & 63) & 48;
    const uint2* tp = (const uint2*)tmp8;
    f32x4 bv0 = *(const f32x4*)(bias + l*8);
    f32x4 bv1 = *(const f32x4*)(bias + l*8 + 4);
    int rg = -1;
    float racc[8];
    #pragma unroll
    for (int j=0;j<8;j++) racc[j] = 0.f;
    #pragma unroll
    for (int i = 0; i < 2; i++){
        int node = blockIdx.x*32 + qid*2 + i;
        if (node < N){
            int e0 = row_off[node], e1 = e0 + deg_in[node];
            f32x2 a01={0.f,0.f}, a23={0.f,0.f}, a45={0.f,0.f}, a67={0.f,0.f};
            spmm_row<false>(tp, csr_src, nullptr, e0, e1, l, qb, a01, a23, a45, a67);
            float isq = rsqrtf((float)max(e1 - e0, 1));
            float r[8];
            r[0] = fmaxf(a01.x*isq + bv0[0], 0.f);
            r[1] = fmaxf(a01.y*isq + bv0[1], 0.f);
            r[2] = fmaxf(a23.x*isq + bv0[2], 0.f);
            r[3] = fmaxf(a23.y*isq + bv0[3], 0.f);
            r[4] = fmaxf(a45.x*isq + bv1[0], 0.f);
            r[5] = fmaxf(a45.y*isq + bv1[1], 0.f);
            r[6] = fmaxf(a67.x*isq + bv1[2], 0.f);
            r[7] = fmaxf(a67.y*isq + bv1[3], 0.f);
            int g = n2g[node];
            if (g != rg){
                if (rg >= 0){
                    #pragma unroll
                    for (int j=0;j<8;j++) atomicAdd(&sacc[rg*FD + l*8 + j], racc[j]);
                }
                rg = g;
                #pragma unroll
                for (int j=0;j<8;j++) racc[j] = 0.f;
            }
            #pragma unroll
            for (int j=0;j<8;j++) racc[j] += r[j];
        }
    }
    if (rg >= 0){
        #pragma unroll
        for (int j=0;j<8;j++) atomicAdd(&sacc[rg*FD + l*8 + j], racc[j]);
    }
    __syncthreads();
    for (int i = tid; i < NG*FD; i += 256){
        float v = sacc[i];
        if (v != 0.f) atomicAdd(&pool[i], v);
    }
    // ---- last-block final: mean -> linear -> softmax (saves a launch) ----
    __threadfence();
    if (tid == 0){
        int done = __hip_atomic_fetch_add(ctr, 1, __ATOMIC_ACQ_REL, __HIP_MEMORY_SCOPE_AGENT);
        isLast = (done == (int)gridDim.x - 1) ? 1 : 0;
    }
    __syncthreads();
    if (!isLast) return;
    if (tid <= NG){
        int lo = 0, hi = N;
        while (lo < hi){ int mid = (lo+hi)>>1; if (n2g[mid] < tid) lo = mid+1; else hi = mid; }
        ub[tid] = lo;
    }
    __syncthreads();
    if (tid < NG*NC){
        int g = tid/NC, c = tid%NC;
        float cntg = (float)max(ub[g+1]-ub[g], 1);
        float inv = 1.f/cntg;
        float acc = bl[c];
        for (int d=0; d<FD; d++){
            float pv = __hip_atomic_load(&pool[g*FD+d], __ATOMIC_RELAXED, __HIP_MEMORY_SCOPE_AGENT);
            acc += pv*inv * Wl[d*NC+c];
        }
        logits[g][c] = acc;
    }
    __syncthreads();
    if (tid < NG*NC){
        int g = tid/NC, c = tid%NC;
        float m = -1e30f;
        for (int i=0;i<NC;i++) m = fmaxf(m, logits[g][i]);
        float ssum = 0.f;
        for (int i=0;i<NC;i++) ssum += expf(logits[g][i]-m);
        out[tid] = expf(logits[g][c]-m)/ssum;
    }
}

extern "C" void kernel_launch(void* const* d_in, const int* in_sizes, int n_in,
                              void* d_out, int out_size, void* d_ws, size_t ws_size,
                              hipStream_t stream) {
    const float* x   = (const float*)d_in[0];
    const int*   ei  = (const int*)d_in[1];
    const int*   n2g = (const int*)d_in[2];
    const float* W1  = (const float*)d_in[3];
    const float* b1  = (const float*)d_in[4];
    const float* W2  = (const float*)d_in[5];
    const float* b2  = (const float*)d_in[6];
    const float* Wl  = (const float*)d_in[7];
    const float* bl  = (const float*)d_in[8];
    float* outp = (float*)d_out;

    int N = in_sizes[2];
    int E = in_sizes[1] / 2;

    int shift = 6;
    while ((((N + (1<<shift) - 1) >> shift) > MAXB) && shift < 10) shift++;
    int B = (N + (1<<shift) - 1) >> shift;
    int C = (E + CHUNK - 1) / CHUNK;
    int meanFill = (int)(((long long)E << shift) / (N > 0 ? N : 1)) + 1;
    int CAP = 4096;
    while (CAP < 3*meanFill) CAP <<= 1;

    char* w = (char*)d_ws;
    size_t off = 0;
    auto alloc = [&](size_t bytes)->char*{ char* p = w + off; off += (bytes + 255) & ~(size_t)255; return p; };
    float*    pool    = (float*)alloc((size_t)NG*FD*4);
    int*      ctr     = (int*)alloc(256);
    int*      deg_in  = (int*)alloc((size_t)N*4);
    int*      row_off = (int*)alloc((size_t)N*4);
    float*    isqo    = (float*)alloc((size_t)N*4);
    int*      bfD     = (int*)alloc((size_t)MAXB*BFPAD*4);
    int*      bfS     = (int*)alloc((size_t)MAXB*BFPAD*4);
    uint16_t* Wf1     = (uint16_t*)alloc(16384*2);
    uint16_t* Wf2     = (uint16_t*)alloc(16384*2);
    uint32_t* tempD   = (uint32_t*)alloc((size_t)B*CAP*4);
    uint16_t* tempS   = (uint16_t*)alloc((size_t)B*CAP*2);
    int*      csr     = (int*)alloc((size_t)B*CAP*4);
    uint8_t*  tmp8    = (uint8_t*)alloc((size_t)N*FD);   // layer-1 fp8 rows (unscaled)
    uint8_t*  tmp8b   = (uint8_t*)alloc((size_t)N*FD);   // layer-2 fp8 rows (pre-scaled by isqo)
    (void)ws_size;

    int gb2 = (N + 255)/256;   // gemm1 blocks (256 rows each)
    int gb  = (N + 31)/32;     // spmm blocks (32 nodes each)

    k_prep        <<<128,       256,  0, stream>>>(W1, W2, Wf1, Wf2, B, bfD, bfS, pool, ctr);
    k_gemm_scatter<<<C + gb2,   1024, 0, stream>>>(ei, E, B, shift, CAP, C,
                                                   bfD, bfS, tempD, tempS,
                                                   x, Wf1, tmp8, N);
    k_build       <<<B,         256,  0, stream>>>(tempD, tempS, bfD, bfS, B, shift, N, CAP,
                                                   row_off, deg_in, isqo, csr);
    k_spmm_gemm   <<<gb,        256,  0, stream>>>(tmp8,  row_off, deg_in, csr, isqo, b1, Wf2, tmp8b, N);
    k_spmm_pool   <<<gb,        256,  0, stream>>>(tmp8b, row_off, deg_in, csr, b2, n2g, pool, N,
                                                   Wl, bl, outp, ctr);
}

// Round 14
// 182.342 us; speedup vs baseline: 1.6843x; 1.6843x over previous
//
#include <hip/hip_runtime.h>
#include <stdint.h>

#define FD 128   // feature dim
#define NG 8     // graphs
#define NC 10    // classes
#define MAXB 1024           // max buckets
#define CHUNK 8192          // edges per sort block (8/thread @ 1024 thr)
#define BFPAD 4             // bucket_fill stride (ints): 4 buckets/64B line

typedef __attribute__((ext_vector_type(8))) short bf16x8;
typedef __attribute__((ext_vector_type(4))) float f32x4;
typedef __attribute__((ext_vector_type(2))) float f32x2;

__device__ __forceinline__ float bf2f(uint16_t u){
    union { uint32_t i; float f; } v; v.i = ((uint32_t)u) << 16; return v.f;
}
__device__ __forceinline__ uint16_t f2bf(float f){
    union { float f; uint32_t i; } v; v.f = f;
    uint32_t r = v.i + 0x7fff + ((v.i >> 16) & 1);
    return (uint16_t)(r >> 16);
}

// ---- fp8 e4m3 conversions (HW path with manual fallback) ----
#if __has_builtin(__builtin_amdgcn_cvt_pk_f32_fp8) && __has_builtin(__builtin_amdgcn_cvt_pk_fp8_f32)
__device__ __forceinline__ f32x2 fp8lo2f(uint32_t p){
    return __builtin_amdgcn_cvt_pk_f32_fp8((int)p, false);
}
__device__ __forceinline__ f32x2 fp8hi2f(uint32_t p){
    return __builtin_amdgcn_cvt_pk_f32_fp8((int)p, true);
}
__device__ __forceinline__ uint32_t pk4fp8(float a, float b, float c, float d){
    int u = 0;
    u = __builtin_amdgcn_cvt_pk_fp8_f32(a, b, u, false);
    u = __builtin_amdgcn_cvt_pk_fp8_f32(c, d, u, true);
    return (uint32_t)u;
}
#else
__device__ __forceinline__ float fp8tof(uint32_t b){
    union { uint32_t i; float f; } v;
    v.i = ((b & 0x7f) << 20) | ((b & 0x80) << 24);
    return v.f * 0x1p120f;
}
__device__ __forceinline__ f32x2 fp8lo2f(uint32_t p){
    return (f32x2){fp8tof(p & 0xff), fp8tof((p >> 8) & 0xff)};
}
__device__ __forceinline__ f32x2 fp8hi2f(uint32_t p){
    return (f32x2){fp8tof((p >> 16) & 0xff), fp8tof((p >> 24) & 0xff)};
}
__device__ __forceinline__ uint32_t f2fp8(float f){
    union { float f; uint32_t i; } v; v.f = f;
    uint32_t s = (v.i >> 24) & 0x80;
    float a = fabsf(f);
    if (a < 0x1p-10f) return s;
    if (a > 448.f) return s | 0x7e;
    v.f = a;
    uint32_t r = v.i + 0x7ffff + ((v.i >> 20) & 1);
    int e = (int)(r >> 23) - 127 + 7;
    uint32_t m = (r >> 20) & 7;
    if (e <= 0){
        uint32_t q = (uint32_t)(a * 512.f + 0.5f);
        return s | (q > 7 ? 8 : q);
    }
    if (e > 15) return s | 0x7e;
    return s | ((uint32_t)e << 3) | m;
}
__device__ __forceinline__ uint32_t pk4fp8(float a, float b, float c, float d){
    return (uint32_t)f2fp8(a) | ((uint32_t)f2fp8(b)<<8) |
           ((uint32_t)f2fp8(c)<<16) | ((uint32_t)f2fp8(d)<<24);
}
#endif

// ============ prep: weight conversion + zero-init ============
__global__ __launch_bounds__(256) void k_prep(const float* __restrict__ W1,
        const float* __restrict__ W2, uint16_t* Wf1, uint16_t* Wf2,
        int B, int* __restrict__ bfD, int* __restrict__ bfS,
        float* __restrict__ pool){
    int t = threadIdx.x;
    int id = blockIdx.x*256 + t;           // grid = 128 blocks -> 32768 threads
    {   // weight fragment conversion (exactly 2*16384 entries)
        int w = id >> 14;
        int r = id & 16383;
        int j = r & 7, frag = r >> 3;
        int lane = frag & 63, t2 = frag >> 6;
        int n = t2 & 7, kk = t2 >> 3;
        int k = kk*32 + (lane>>4)*8 + j;
        int col = n*16 + (lane&15);
        float v = (w ? W2 : W1)[k*128 + col];
        (w ? Wf2 : Wf1)[r] = f2bf(v);
    }
    for (int i = id; i < B*BFPAD; i += 32768){ bfD[i] = 0; bfS[i] = 0; }
    if (id < NG*FD) pool[id] = 0.f;
}

// ============ FUSED: merged D+S sort | GEMM1 (2 block ranges) ============
// R8/R12-validated: edge-pass cost ~ per-block fixed work + packed 16B
// stores. R13's CHUNK 8192 halves sort-block instances (98) so LDS init,
// scans and reserve passes amortize over 2x edges. (R13's last-block-final
// fusion REVERTED: its device-scope threadfence x1563 blocks invalidated
// the non-coherent per-XCD L2s every block -> gather refetch from HBM,
// +120us. Fences in hot kernels are forbidden on multi-XCD parts.)
__global__ __launch_bounds__(1024) void k_gemm_scatter(const int* __restrict__ ei,
        int E, int B, int shift, int CAP, int C,
        int* __restrict__ bfD, int* __restrict__ bfS,
        uint32_t* __restrict__ tempD, uint16_t* __restrict__ tempS,
        const float* __restrict__ X, const uint16_t* __restrict__ Wf,
        uint8_t* __restrict__ out8, int N){
    __shared__ __align__(16) char lds[61440];
    int t = threadIdx.x;
    int lmask = (1<<shift) - 1;
    if ((int)blockIdx.x < C){
        uint32_t* payD = (uint32_t*)lds;          // 11264 u32 = 45056B
        uint16_t* payS = (uint16_t*)lds;          // 15360 u16 = 30720B (reuse)
        int* cnt  = (int*)(lds + 45056);
        int* off  = cnt  + MAXB;
        int* resv = off  + MAXB;
        int* scr  = resv + MAXB;                  // + 16384B = 61440
        // ---- read chunk ONCE ----
        int c = blockIdx.x;
        int e0 = c*CHUNK, e1 = min(E, e0+CHUNK);
        int ss[8], dd[8];
        #pragma unroll
        for (int k=0;k<8;k++){
            int e = e0 + t + k*1024;
            bool ok = e < e1;
            ss[k] = ok ? ei[e]   : -1;
            dd[k] = ok ? ei[E+e] : -1;
        }
        // ---------- D phase: (loc<<20|src) u32, pad-4 ----------
        for (int i=t;i<11264;i+=1024) payD[i] = 0xFFFFFFFFu;
        for (int i=t;i<B;i+=1024) cnt[i] = 0;
        __syncthreads();
        int bb[8], pl[8];
        #pragma unroll
        for (int k=0;k<8;k++){
            bb[k] = -1;
            if (dd[k] >= 0){
                int b = dd[k] >> shift;
                bb[k] = b;
                pl[k] = atomicAdd(&cnt[b], 1);
            }
        }
        __syncthreads();
        int v = (t < B) ? ((cnt[t]+3) & ~3) : 0;
        scr[t] = v; __syncthreads();
        for (int o=1;o<1024;o<<=1){ int u=(t>=o)?scr[t-o]:0; __syncthreads(); scr[t]+=u; __syncthreads(); }
        if (t < B) off[t] = scr[t] - v;
        __syncthreads();
        int totalPad = scr[1023];
        #pragma unroll
        for (int k=0;k<8;k++)
            if (bb[k] >= 0)
                payD[off[bb[k]] + pl[k]] = ((uint32_t)(dd[k] & lmask) << 20) | (uint32_t)ss[k];
        for (int b=t;b<B;b+=1024){
            int pc = (cnt[b]+3) & ~3;
            resv[b] = pc ? atomicAdd(&bfD[b*BFPAD], pc) : 0;
        }
        __syncthreads();
        for (int g=t; g < (totalPad>>2); g += 1024){
            int pos = g << 2;
            int lo = 0, hi = B-1;   // largest b with off[b] <= pos
            while (lo < hi){ int mid=(lo+hi+1)>>1; if (off[mid] <= pos) lo = mid; else hi = mid-1; }
            int rel = resv[lo] + (pos - off[lo]);
            if (rel + 4 <= CAP){
                uint4 w4 = *(const uint4*)&payD[pos];
                *(uint4*)&tempD[(size_t)lo*CAP + rel] = w4;
            }
        }
        __syncthreads();   // all payD/off/resv reads done before LDS reuse
        // ---------- S phase: (src&lmask) u16, pad-8 ----------
        for (int i=t;i<15360;i+=1024) payS[i] = 0xFFFF;
        for (int i=t;i<B;i+=1024) cnt[i] = 0;
        __syncthreads();
        #pragma unroll
        for (int k=0;k<8;k++){
            bb[k] = -1;
            if (ss[k] >= 0){
                int b = ss[k] >> shift;
                bb[k] = b;
                pl[k] = atomicAdd(&cnt[b], 1);
            }
        }
        __syncthreads();
        v = (t < B) ? ((cnt[t]+7) & ~7) : 0;
        scr[t] = v; __syncthreads();
        for (int o=1;o<1024;o<<=1){ int u=(t>=o)?scr[t-o]:0; __syncthreads(); scr[t]+=u; __syncthreads(); }
        if (t < B) off[t] = scr[t] - v;
        __syncthreads();
        totalPad = scr[1023];
        #pragma unroll
        for (int k=0;k<8;k++)
            if (bb[k] >= 0) payS[off[bb[k]] + pl[k]] = (uint16_t)(ss[k] & lmask);
        for (int b=t;b<B;b+=1024){
            int pc = (cnt[b]+7) & ~7;
            resv[b] = pc ? atomicAdd(&bfS[b*BFPAD], pc) : 0;
        }
        __syncthreads();
        for (int g=t; g < (totalPad>>3); g += 1024){
            int pos = g << 3;
            int lo = 0, hi = B-1;
            while (lo < hi){ int mid=(lo+hi+1)>>1; if (off[mid] <= pos) lo = mid; else hi = mid-1; }
            int rel = resv[lo] + (pos - off[lo]);
            if (rel + 8 <= CAP){
                uint4 w4 = *(const uint4*)&payS[pos];
                *(uint4*)&tempS[(size_t)lo*CAP + rel] = w4;
            }
        }
        return;
    }
    // ---------------- GEMM1 path: 256 rows/block, 16 waves ----------------
    int wave = t>>6, lane = t&63, quad = lane>>4, low = lane&15;
    int rowA  = (blockIdx.x - C)*256 + wave*16 + low;
    int rowAc = min(rowA, N-1);
    const float* arow = X + (size_t)rowAc*FD;
    bf16x8 ah[4];
    #pragma unroll
    for (int kk=0;kk<4;kk++){
        f32x4 f0 = *(const f32x4*)(arow + kk*32 + quad*8);
        f32x4 f1 = *(const f32x4*)(arow + kk*32 + quad*8 + 4);
        #pragma unroll
        for (int j=0;j<4;j++) ah[kk][j]   = (short)f2bf(f0[j]);
        #pragma unroll
        for (int j=0;j<4;j++) ah[kk][j+4] = (short)f2bf(f1[j]);
    }
    f32x4 acc[8];
    #pragma unroll
    for (int n=0;n<8;n++) acc[n] = (f32x4){0.f,0.f,0.f,0.f};
    #pragma unroll
    for (int kk=0;kk<4;kk++){
        #pragma unroll
        for (int n=0;n<8;n++){
            bf16x8 bh = *(const bf16x8*)(Wf + ((size_t)((kk*8+n)*64 + lane))*8);
            acc[n] = __builtin_amdgcn_mfma_f32_16x16x32_bf16(bh, ah[kk], acc[n], 0, 0, 0);
        }
    }
    if (rowA < N){
        uint8_t* orow = out8 + (size_t)rowA*FD;
        #pragma unroll
        for (int n=0;n<8;n++){
            uint32_t pk = pk4fp8(acc[n][0], acc[n][1], acc[n][2], acc[n][3]);
            *(uint32_t*)(orow + n*16 + quad*4) = pk;
        }
    }
}

// ============ per-bucket build: row_off/deg_in/csr from tempD; isqo from tempS ============
__global__ __launch_bounds__(256) void k_build(const uint32_t* __restrict__ tempD,
        const uint16_t* __restrict__ tempS,
        const int* __restrict__ bfD, const int* __restrict__ bfS,
        int B, int shift, int N, int CAP,
        int* __restrict__ row_off, int* __restrict__ deg_in,
        float* __restrict__ isqo, int* __restrict__ csr){
    __shared__ int cnt_[MAXB];
    __shared__ int off_[MAXB];
    int b = blockIdx.x, t = threadIdx.x;
    int range = 1<<shift, nb0 = b<<shift;
    int fill = min(bfD[b*BFPAD], CAP);
    const uint32_t* seg = tempD + (size_t)b*CAP;
    for (int i=t;i<range;i+=256) cnt_[i]=0;
    __syncthreads();
    for (int i=t;i<fill;i+=256){
        int loc = (int)(seg[i] >> 20);
        if (loc < range) atomicAdd(&cnt_[loc], 1);   // skip pad sentinels
    }
    __syncthreads();
    if (range == 64){
        if (t < 64){
            int v = cnt_[t];
            int inc = v;
            #pragma unroll
            for (int o=1;o<64;o<<=1){
                int u = __shfl_up(inc, o);
                if (t >= o) inc += u;
            }
            off_[t] = inc - v;
        }
    } else if (t == 0){
        int run = 0;
        for (int i=0;i<range;i++){ off_[i]=run; run+=cnt_[i]; }
    }
    __syncthreads();
    int base = b*CAP;
    for (int i=t;i<range;i+=256){
        int node = nb0 + i;
        if (node < N){
            row_off[node] = base + off_[i];
            deg_in[node]  = cnt_[i];
        }
    }
    __syncthreads();
    int* csrb = csr + (size_t)base;
    for (int i=t;i<fill;i+=256){
        uint32_t v = seg[i];
        int loc = (int)(v >> 20);
        if (loc < range){
            int p = atomicAdd(&off_[loc], 1);
            csrb[p] = (int)(v & 0xFFFFFu);
        }
    }
    __syncthreads();
    // ---- phase B: out-degree histogram from sorted src stream ----
    for (int i=t;i<range;i+=256) cnt_[i]=0;
    __syncthreads();
    int fillS = min(bfS[b*BFPAD], CAP);
    const uint16_t* segS = tempS + (size_t)b*CAP;
    for (int i=t;i<fillS;i+=256){
        int v = (int)segS[i];
        if (v < range) atomicAdd(&cnt_[v], 1);
    }
    __syncthreads();
    for (int i=t;i<range;i+=256){
        int node = nb0 + i;
        if (node < N) isqo[node] = rsqrtf((float)max(cnt_[i], 1));
    }
}

// ============ SpMM row-gather core: quarter-wave, 8B/lane, depth-8 ============
template<bool WSCALE>
__device__ __forceinline__ void spmm_row(const uint2* __restrict__ tp,
        const int* __restrict__ csr_src, const float* __restrict__ isqo,
        int e0, int e1, int l, int qb,
        f32x2& a01, f32x2& a23, f32x2& a45, f32x2& a67){
    for (int base = e0; base < e1; base += 16){
        int my = 0;
        if (base + l < e1) my = csr_src[base + l];
        int cnt = min(16, e1 - base);
        for (int j0 = 0; j0 < cnt; j0 += 8){
            int ss[8];
            #pragma unroll
            for (int k=0;k<8;k++)
                ss[k] = __shfl(my, qb + min(j0 + k, cnt-1));
            uint2 p[8]; float w[8];
            #pragma unroll
            for (int k=0;k<8;k++)
                p[k] = tp[(size_t)ss[k]*16 + l];
            if (WSCALE){
                #pragma unroll
                for (int k=0;k<8;k++) w[k] = isqo[ss[k]];
            }
            #pragma unroll
            for (int k=0;k<8;k++){
                if (j0 + k < cnt){
                    if (WSCALE){
                        a01 += fp8lo2f(p[k].x)*w[k]; a23 += fp8hi2f(p[k].x)*w[k];
                        a45 += fp8lo2f(p[k].y)*w[k]; a67 += fp8hi2f(p[k].y)*w[k];
                    } else {
                        a01 += fp8lo2f(p[k].x); a23 += fp8hi2f(p[k].x);
                        a45 += fp8lo2f(p[k].y); a67 += fp8hi2f(p[k].y);
                    }
                }
            }
        }
    }
}

// ============ Fused: SpMM layer-1 -> LDS h -> GEMM W2 -> fp8 (scaled) ============
__global__ __launch_bounds__(256, 6) void k_spmm_gemm(const uint8_t* __restrict__ tmp8,
        const int* __restrict__ row_off, const int* __restrict__ deg_in,
        const int* __restrict__ csr_src, const float* __restrict__ isqo,
        const float* __restrict__ bias, const uint16_t* __restrict__ Wf,
        uint8_t* __restrict__ out8, int N){
    __shared__ __align__(16) uint16_t hsrow[32][136];   // +8 shorts pad
    int tid = threadIdx.x;
    int l = tid & 15, qid = tid >> 4, qb = (tid & 63) & 48;
    const uint2* tp = (const uint2*)tmp8;
    f32x4 bv0 = *(const f32x4*)(bias + l*8);
    f32x4 bv1 = *(const f32x4*)(bias + l*8 + 4);
    #pragma unroll
    for (int i = 0; i < 2; i++){
        int rowL = qid*2 + i;
        int node = blockIdx.x*32 + rowL;
        int e0 = 0, e1 = 0;
        if (node < N){ e0 = row_off[node]; e1 = e0 + deg_in[node]; }
        f32x2 a01={0.f,0.f}, a23={0.f,0.f}, a45={0.f,0.f}, a67={0.f,0.f};
        spmm_row<true>(tp, csr_src, isqo, e0, e1, l, qb, a01, a23, a45, a67);
        float isq = rsqrtf((float)max(e1 - e0, 1));
        float r0 = fmaxf(a01.x*isq + bv0[0], 0.f);
        float r1 = fmaxf(a01.y*isq + bv0[1], 0.f);
        float r2 = fmaxf(a23.x*isq + bv0[2], 0.f);
        float r3 = fmaxf(a23.y*isq + bv0[3], 0.f);
        float r4 = fmaxf(a45.x*isq + bv1[0], 0.f);
        float r5 = fmaxf(a45.y*isq + bv1[1], 0.f);
        float r6 = fmaxf(a67.x*isq + bv1[2], 0.f);
        float r7 = fmaxf(a67.y*isq + bv1[3], 0.f);
        uint4 o;
        o.x = (uint32_t)f2bf(r0) | ((uint32_t)f2bf(r1) << 16);
        o.y = (uint32_t)f2bf(r2) | ((uint32_t)f2bf(r3) << 16);
        o.z = (uint32_t)f2bf(r4) | ((uint32_t)f2bf(r5) << 16);
        o.w = (uint32_t)f2bf(r6) | ((uint32_t)f2bf(r7) << 16);
        if (node >= N) o = (uint4){0u,0u,0u,0u};
        *(uint4*)(&hsrow[rowL][l*8]) = o;
    }
    __syncthreads();
    int wave = tid>>6, lane = tid&63, quad = lane>>4, low = lane&15;
    int rowL = (wave&1)*16 + low;
    int rowA = blockIdx.x*32 + rowL;
    int nb0 = (wave>>1)*4;
    bf16x8 ah[4];
    #pragma unroll
    for (int kk=0;kk<4;kk++)
        ah[kk] = *(const bf16x8*)(&hsrow[rowL][kk*32 + quad*8]);
    f32x4 acc[4];
    #pragma unroll
    for (int n=0;n<4;n++) acc[n] = (f32x4){0.f,0.f,0.f,0.f};
    #pragma unroll
    for (int kk=0;kk<4;kk++){
        #pragma unroll
        for (int n2=0;n2<4;n2++){
            int n = nb0 + n2;
            bf16x8 bh = *(const bf16x8*)(Wf + ((size_t)((kk*8+n)*64 + lane))*8);
            acc[n2] = __builtin_amdgcn_mfma_f32_16x16x32_bf16(bh, ah[kk], acc[n2], 0, 0, 0);
        }
    }
    if (rowA < N){
        float sc = isqo[rowA];   // fold out-deg scale: spmm_pool needs no isqo loads
        uint8_t* orow = out8 + (size_t)rowA*FD;
        #pragma unroll
        for (int n2=0;n2<4;n2++){
            int n = nb0 + n2;
            uint32_t pk = pk4fp8(acc[n2][0]*sc, acc[n2][1]*sc, acc[n2][2]*sc, acc[n2][3]*sc);
            *(uint32_t*)(orow + n*16 + quad*4) = pk;
        }
    }
}

// ============ Fused: SpMM layer-2 -> per-graph pool (32 nodes/block) ============
__global__ __launch_bounds__(256, 6) void k_spmm_pool(const uint8_t* __restrict__ tmp8,
        const int* __restrict__ row_off, const int* __restrict__ deg_in,
        const int* __restrict__ csr_src,
        const float* __restrict__ bias, const int* __restrict__ n2g,
        float* __restrict__ pool, int N){
    __shared__ float sacc[NG*FD];
    int tid = threadIdx.x;
    for (int i = tid; i < NG*FD; i += 256) sacc[i] = 0.f;
    __syncthreads();
    int l = tid & 15, qid = tid >> 4, qb = (tid & 63) & 48;
    const uint2* tp = (const uint2*)tmp8;
    f32x4 bv0 = *(const f32x4*)(bias + l*8);
    f32x4 bv1 = *(const f32x4*)(bias + l*8 + 4);
    int rg = -1;
    float racc[8];
    #pragma unroll
    for (int j=0;j<8;j++) racc[j] = 0.f;
    #pragma unroll
    for (int i = 0; i < 2; i++){
        int node = blockIdx.x*32 + qid*2 + i;
        if (node < N){
            int e0 = row_off[node], e1 = e0 + deg_in[node];
            f32x2 a01={0.f,0.f}, a23={0.f,0.f}, a45={0.f,0.f}, a67={0.f,0.f};
            spmm_row<false>(tp, csr_src, nullptr, e0, e1, l, qb, a01, a23, a45, a67);
            float isq = rsqrtf((float)max(e1 - e0, 1));
            float r[8];
            r[0] = fmaxf(a01.x*isq + bv0[0], 0.f);
            r[1] = fmaxf(a01.y*isq + bv0[1], 0.f);
            r[2] = fmaxf(a23.x*isq + bv0[2], 0.f);
            r[3] = fmaxf(a23.y*isq + bv0[3], 0.f);
            r[4] = fmaxf(a45.x*isq + bv1[0], 0.f);
            r[5] = fmaxf(a45.y*isq + bv1[1], 0.f);
            r[6] = fmaxf(a67.x*isq + bv1[2], 0.f);
            r[7] = fmaxf(a67.y*isq + bv1[3], 0.f);
            int g = n2g[node];
            if (g != rg){
                if (rg >= 0){
                    #pragma unroll
                    for (int j=0;j<8;j++) atomicAdd(&sacc[rg*FD + l*8 + j], racc[j]);
                }
                rg = g;
                #pragma unroll
                for (int j=0;j<8;j++) racc[j] = 0.f;
            }
            #pragma unroll
            for (int j=0;j<8;j++) racc[j] += r[j];
        }
    }
    if (rg >= 0){
        #pragma unroll
        for (int j=0;j<8;j++) atomicAdd(&sacc[rg*FD + l*8 + j], racc[j]);
    }
    __syncthreads();
    for (int i = tid; i < NG*FD; i += 256){
        float v = sacc[i];
        if (v != 0.f) atomicAdd(&pool[i], v);
    }
}

// ============ mean, linear, softmax -> 80 f32 ============
__global__ __launch_bounds__(128) void k_final(const float* __restrict__ pool,
        const int* __restrict__ n2g, int N, const float* __restrict__ Wl,
        const float* __restrict__ bl, float* __restrict__ out){
    __shared__ int ub[NG+1];
    __shared__ float logits[NG][NC];
    int t = threadIdx.x;
    if (t <= NG){
        int lo = 0, hi = N;
        while (lo < hi){ int mid = (lo+hi)>>1; if (n2g[mid] < t) lo = mid+1; else hi = mid; }
        ub[t] = lo;
    }
    __syncthreads();
    if (t < NG*NC){
        int g = t/NC, c = t%NC;
        float cnt = (float)max(ub[g+1]-ub[g], 1);
        float inv = 1.f/cnt;
        float acc = bl[c];
        for (int d=0; d<FD; d++)
            acc += pool[g*FD+d]*inv * Wl[d*NC+c];
        logits[g][c] = acc;
    }
    __syncthreads();
    if (t < NG*NC){
        int g = t/NC, c = t%NC;
        float m = -1e30f;
        for (int i=0;i<NC;i++) m = fmaxf(m, logits[g][i]);
        float ssum = 0.f;
        for (int i=0;i<NC;i++) ssum += expf(logits[g][i]-m);
        out[t] = expf(logits[g][c]-m)/ssum;
    }
}

extern "C" void kernel_launch(void* const* d_in, const int* in_sizes, int n_in,
                              void* d_out, int out_size, void* d_ws, size_t ws_size,
                              hipStream_t stream) {
    const float* x   = (const float*)d_in[0];
    const int*   ei  = (const int*)d_in[1];
    const int*   n2g = (const int*)d_in[2];
    const float* W1  = (const float*)d_in[3];
    const float* b1  = (const float*)d_in[4];
    const float* W2  = (const float*)d_in[5];
    const float* b2  = (const float*)d_in[6];
    const float* Wl  = (const float*)d_in[7];
    const float* bl  = (const float*)d_in[8];
    float* outp = (float*)d_out;

    int N = in_sizes[2];
    int E = in_sizes[1] / 2;

    int shift = 6;
    while ((((N + (1<<shift) - 1) >> shift) > MAXB) && shift < 10) shift++;
    int B = (N + (1<<shift) - 1) >> shift;
    int C = (E + CHUNK - 1) / CHUNK;
    int meanFill = (int)(((long long)E << shift) / (N > 0 ? N : 1)) + 1;
    int CAP = 4096;
    while (CAP < 3*meanFill) CAP <<= 1;

    char* w = (char*)d_ws;
    size_t off = 0;
    auto alloc = [&](size_t bytes)->char*{ char* p = w + off; off += (bytes + 255) & ~(size_t)255; return p; };
    float*    pool    = (float*)alloc((size_t)NG*FD*4);
    int*      deg_in  = (int*)alloc((size_t)N*4);
    int*      row_off = (int*)alloc((size_t)N*4);
    float*    isqo    = (float*)alloc((size_t)N*4);
    int*      bfD     = (int*)alloc((size_t)MAXB*BFPAD*4);
    int*      bfS     = (int*)alloc((size_t)MAXB*BFPAD*4);
    uint16_t* Wf1     = (uint16_t*)alloc(16384*2);
    uint16_t* Wf2     = (uint16_t*)alloc(16384*2);
    uint32_t* tempD   = (uint32_t*)alloc((size_t)B*CAP*4);
    uint16_t* tempS   = (uint16_t*)alloc((size_t)B*CAP*2);
    int*      csr     = (int*)alloc((size_t)B*CAP*4);
    uint8_t*  tmp8    = (uint8_t*)alloc((size_t)N*FD);   // layer-1 fp8 rows (unscaled)
    uint8_t*  tmp8b   = (uint8_t*)alloc((size_t)N*FD);   // layer-2 fp8 rows (pre-scaled by isqo)
    (void)ws_size;

    int gb2 = (N + 255)/256;   // gemm1 blocks (256 rows each)
    int gb  = (N + 31)/32;     // spmm blocks (32 nodes each)

    k_prep        <<<128,       256,  0, stream>>>(W1, W2, Wf1, Wf2, B, bfD, bfS, pool);
    k_gemm_scatter<<<C + gb2,   1024, 0, stream>>>(ei, E, B, shift, CAP, C,
                                                   bfD, bfS, tempD, tempS,
                                                   x, Wf1, tmp8, N);
    k_build       <<<B,         256,  0, stream>>>(tempD, tempS, bfD, bfS, B, shift, N, CAP,
                                                   row_off, deg_in, isqo, csr);
    k_spmm_gemm   <<<gb,        256,  0, stream>>>(tmp8,  row_off, deg_in, csr, isqo, b1, Wf2, tmp8b, N);
    k_spmm_pool   <<<gb,        256,  0, stream>>>(tmp8b, row_off, deg_in, csr, b2, n2g, pool, N);
    k_final       <<<1,         128,  0, stream>>>(pool, n2g, N, Wl, bl, outp);
}